// Round 11
// baseline (142.276 us; speedup 1.0000x reference)
//
#include <hip/hip_runtime.h>
#include <stdint.h>

// Problem constants (SelfAttention: B=8, C=512, C8=64, W=2048)
#define B_  8
#define C_  512
#define CO_ 64
#define W_  2048
#define R_  640   // stacked projection rows: 64 q + 64 k + 512 v
#define LOG2E 1.4426950408889634f

typedef float f32x4 __attribute__((ext_vector_type(4)));
typedef float f32x16 __attribute__((ext_vector_type(16)));
typedef __bf16 bf16x8 __attribute__((ext_vector_type(8)));
typedef __bf16 bf16x2 __attribute__((ext_vector_type(2)));
typedef unsigned u32x2 __attribute__((ext_vector_type(2)));
typedef unsigned u32x4 __attribute__((ext_vector_type(4)));
typedef unsigned short u16;
typedef u16 u16x8 __attribute__((ext_vector_type(8)));
typedef u16 u16x4 __attribute__((ext_vector_type(4)));

static __device__ __forceinline__ float exp2g(float f){
  return __builtin_amdgcn_exp2f(f);    // v_exp_f32 (2^x)
}
static __device__ __forceinline__ u16 f2b(float f){
  union { float f; unsigned u; } v; v.f = f;
  unsigned r = v.u + 0x7FFFu + ((v.u >> 16) & 1u);  // RNE
  return (u16)(r >> 16);
}
static __device__ __forceinline__ bf16x8 ldb(const u16* p){
  return __builtin_bit_cast(bf16x8, *(const u16x8*)p);
}
static __device__ __forceinline__ f32x4 mfma16(bf16x8 a, bf16x8 b, f32x4 c){
  return __builtin_amdgcn_mfma_f32_16x16x32_bf16(a, b, c, 0, 0, 0);
}
static __device__ __forceinline__ f32x16 mfma32(bf16x8 a, bf16x8 b, f32x16 c){
  return __builtin_amdgcn_mfma_f32_32x32x16_bf16(a, b, c, 0, 0, 0);
}
// v_permlane32_swap_b32: vdst lanes[32:63] <-> vsrc lanes[0:31]
static __device__ __forceinline__ void pl32swap(unsigned &a, unsigned &b){
  asm("v_permlane32_swap_b32 %0, %1" : "+v"(a), "+v"(b));
}
static __device__ __forceinline__ float red_sum32(float v){
  unsigned a = __builtin_bit_cast(unsigned, v), b = a;
  pl32swap(a, b);
  return __builtin_bit_cast(float, a) + __builtin_bit_cast(float, b);
}
static __device__ __forceinline__ unsigned pkbf(float lo, float hi){
  bf16x2 t; t[0] = (__bf16)lo; t[1] = (__bf16)hi;
  return __builtin_bit_cast(unsigned, t);
}

// ---------------- K0: stack + cast weights/bias to bf16 ----------------
// Q rows are pre-scaled by log2(e) so attention softmax can use raw exp2.
__global__ __launch_bounds__(256) void prep_w(
    const float* __restrict__ Wq, const float* __restrict__ bq,
    const float* __restrict__ Wk, const float* __restrict__ bk,
    const float* __restrict__ Wv, const float* __restrict__ bv,
    u16* __restrict__ Wall, float* __restrict__ ball){
  int e = blockIdx.x * 256 + threadIdx.x;
  if (e < R_ * C_){
    int r = e >> 9, c = e & (C_ - 1);
    float w;
    if (r < 64)       w = Wq[r * C_ + c] * LOG2E;
    else if (r < 128) w = Wk[(r - 64) * C_ + c];
    else              w = Wv[(r - 128) * C_ + c];
    Wall[e] = f2b(w);
  }
  if (e < R_){
    float bb;
    if (e < 64)       bb = bq[e] * LOG2E;
    else if (e < 128) bb = bk[e - 64];
    else              bb = bv[e - 128];
    ball[e] = bb;
  }
}

// ---------------- K1: x [b][c][w] f32 -> xbT [b][w][c] bf16 ----------------
__global__ __launch_bounds__(256) void xpose(const float* __restrict__ x,
                                             u16* __restrict__ xbT){
  __shared__ float t[32][33];
  int b = blockIdx.z, c0 = blockIdx.y * 32, w0 = blockIdx.x * 32;
  int tx = threadIdx.x & 31, ty = threadIdx.x >> 5;   // ty 0..7
  const float* xb = x + (size_t)b * C_ * W_;
  #pragma unroll
  for (int k = 0; k < 4; k++)
    t[ty + k * 8][tx] = xb[(size_t)(c0 + ty + k * 8) * W_ + w0 + tx];
  __syncthreads();
  u16* ob = xbT + (size_t)b * W_ * C_;
  #pragma unroll
  for (int k = 0; k < 4; k++)
    ob[(size_t)(w0 + ty + k * 8) * C_ + c0 + tx] = f2b(t[tx][ty + k * 8]);
}

// ---------------- K2: fused projection GEMM ----------------
// Outputs stored FRAGMENT-MAJOR for the attention kernel's 32x32 MFMA:
//  Q/K: f[(w/32)][(o/16)][lane=((o>>3)&1)*32 + (w&31)][e=o&7]  (1KB/frag)
//  V:   f[(c/32)][(j/16)][lane=((j>>3)&1)*32 + (c&31)][e=j&7]  (1KB/frag)
#define PADW 40
__global__ __launch_bounds__(256) void gemm_proj(
    const u16* __restrict__ Wall, const float* __restrict__ ball,
    const u16* __restrict__ xbT, u16* __restrict__ qf,
    u16* __restrict__ kf, u16* __restrict__ vf){
  __shared__ u16 at[64][PADW];
  __shared__ u16 bt[64][PADW];
  int b = blockIdx.z;
  int m0 = blockIdx.y * 64, n0 = blockIdx.x * 64;
  int tid = threadIdx.x, lane = tid & 63, wid = tid >> 6;
  int wm = wid >> 1, wn = wid & 1;
  int g = lane >> 4, r = lane & 15;
  const u16* xb = xbT + (size_t)b * W_ * C_;
  f32x4 acc[2][2] = {};
  int srow = tid >> 2, sseg = (tid & 3) * 8;
  for (int kk = 0; kk < 16; kk++){
    int c0 = kk * 32;
    *(u16x8*)&at[srow][sseg] = *(const u16x8*)&Wall[(size_t)(m0 + srow) * C_ + c0 + sseg];
    *(u16x8*)&bt[srow][sseg] = *(const u16x8*)&xb[(size_t)(n0 + srow) * C_ + c0 + sseg];
    __syncthreads();
    bf16x8 a0 = ldb(&at[wm * 32 +  0 + r][g * 8]);
    bf16x8 a1 = ldb(&at[wm * 32 + 16 + r][g * 8]);
    bf16x8 b0 = ldb(&bt[wn * 32 +  0 + r][g * 8]);
    bf16x8 b1 = ldb(&bt[wn * 32 + 16 + r][g * 8]);
    acc[0][0] = mfma16(a0, b0, acc[0][0]);
    acc[0][1] = mfma16(a0, b1, acc[0][1]);
    acc[1][0] = mfma16(a1, b0, acc[1][0]);
    acc[1][1] = mfma16(a1, b1, acc[1][1]);
    __syncthreads();
  }
  // epilogue: bias + store fragment-major
  #pragma unroll
  for (int i = 0; i < 2; i++){
    #pragma unroll
    for (int n = 0; n < 2; n++){
      int rbase = m0 + wm * 32 + i * 16 + g * 4;       // stacked row (o or c+128)
      int wcol  = n0 + wn * 32 + n * 16 + r;           // w (i or j)
      if (m0 < 128){
        u16* base = (m0 == 0 ? qf : kf) + (size_t)b * W_ * CO_;
        int o0 = (rbase & 63);
        int oc = o0 >> 4, h2 = (o0 >> 3) & 1, e0 = o0 & 7;
        u16x4 pk;
        #pragma unroll
        for (int t = 0; t < 4; t++) pk[t] = f2b(acc[i][n][t] + ball[rbase + t]);
        *(u16x4*)&base[((size_t)((wcol >> 5) * 4 + oc) * 64 + h2 * 32 + (wcol & 31)) * 8 + e0] = pk;
      } else {
        u16* vb = vf + (size_t)b * C_ * W_;
        int jt = wcol >> 4, h2 = (wcol >> 3) & 1, e = wcol & 7;
        #pragma unroll
        for (int t = 0; t < 4; t++){
          int c = rbase + t - 128;
          vb[((size_t)((c >> 5) * (W_ / 16) + jt) * 64 + h2 * 32 + (c & 31)) * 8 + e] =
              f2b(acc[i][n][t] + ball[rbase + t]);
        }
      }
    }
  }
}

// ---------------- K3: P-shared flash attention v10 ----------------
// 1024 blocks x 256 thr. b=bid&7, u=bid>>3: i0=(u&63)*32, chalf=u>>6.
// 4 waves share (b,i0,chalf); wave wv owns c = chalf*256 + wv*64 (2 c-tiles).
// Macro-iter m (16 total, 4 j-tiles each): wave wv computes S for j-tile
// 4m+wv ONCE (no-max exp2 softmax), writes P[i][j] to LDS (double-buffered,
// XOR-swizzled j^=(li&7)<<3, stride 132 -> 2-way banks = free); barrier;
// all waves PV all 4 tiles from LDS. S-redundancy 8x -> 2x, chains 4x down.
__global__ __launch_bounds__(256, 4) void attn10(
    const u16* __restrict__ qf, const u16* __restrict__ kf,
    const u16* __restrict__ vf, const float* __restrict__ x,
    const float* __restrict__ gamma, float* __restrict__ out){
  __shared__ u16 pb[2][32][132];      // P double buffer, [i][j(swizzled)]
  __shared__ float lredf[4][32];      // per-wave row-sum partials
  int tid = threadIdx.x, lane = tid & 63, wv = tid >> 6;
  int bid = blockIdx.x;
  int b = bid & 7;
  int u = bid >> 3;                    // 0..127
  int i0 = (u & 63) * 32;
  int cbase = (u >> 6) * 256 + wv * 64;
  int li = lane & 31, hi = lane >> 5;
  int swz = (li & 7) << 3;             // XOR key, bits 3..5 of j
  const u16* qfb = qf + (size_t)b * W_ * CO_;
  const u16* kfb = kf + (size_t)b * W_ * CO_;
  const u16* vfb = vf + (size_t)b * C_ * W_;

  // Q B-frags: qf[(i0/32)][oc][lane][8]
  bf16x8 fq[4];
  {
    const u16* qp = &qfb[(size_t)(i0 >> 5) * 4 * 512 + lane * 8];
    #pragma unroll
    for (int oc = 0; oc < 4; oc++) fq[oc] = ldb(qp + oc * 512);
  }

  // streaming bases: K for this wave's own j-tiles (4m+wv); V for c-slice
  const u16* kp = &kfb[(size_t)wv * 2048 + lane * 8];   // += 8192 per macro
  const u16* vp0 = &vfb[(size_t)(cbase >> 5) * (W_ / 16) * 512 + lane * 8];
  const u16* vp1 = vp0 + (size_t)(W_ / 16) * 512;       // += 4096 per macro

  f32x16 acc0 = {}, acc1 = {};
  f32x4 lacc = {};

  // softmax + P-write for one j-tile from fk, into buffer bsel
  auto sphase = [&](bf16x8 (&fk)[4], int bsel){
    f32x16 S = {};
    S = mfma32(fk[0], fq[0], S);
    S = mfma32(fk[1], fq[1], S);
    S = mfma32(fk[2], fq[2], S);
    S = mfma32(fk[3], fq[3], S);
    float p[16];
    #pragma unroll
    for (int t = 0; t < 16; t++) p[t] = exp2g(S[t]);
    #pragma unroll
    for (int t = 0; t < 4; t++)
      lacc[t] += ((p[t] + p[4 + t]) + (p[8 + t] + p[12 + t]));
    // write 4x b64: p[4B..4B+3] -> j = wv*32 + 8*B + 4*hi (+swizzle)
    #pragma unroll
    for (int B = 0; B < 4; B++){
      unsigned lo = pkbf(p[4 * B + 0], p[4 * B + 1]);
      unsigned h2 = pkbf(p[4 * B + 2], p[4 * B + 3]);
      int j0 = (wv * 32 + 8 * B + 4 * hi) ^ swz;
      u32x2 wpair = {lo, h2};
      *(u32x2*)&pb[bsel][li][j0] = wpair;
    }
  };
  // read P B-frag for (j-tile jj, K-chunk kj) from buffer bsel
  auto pfrag = [&](int bsel, int jj, int kj) -> bf16x8 {
    int j0 = (jj * 32 + kj * 16 + 8 * hi) ^ swz;
    u16x4 a = *(const u16x4*)&pb[bsel][li][j0];
    u16x4 c = *(const u16x4*)&pb[bsel][li][j0 + 4];
    u16x8 w = {a[0], a[1], a[2], a[3], c[0], c[1], c[2], c[3]};
    return __builtin_bit_cast(bf16x8, w);
  };

  // prologue: S(macro 0) -> buf 0
  {
    bf16x8 fk[4];
    #pragma unroll
    for (int oc = 0; oc < 4; oc++) fk[oc] = ldb(kp + oc * 512);
    sphase(fk, 0);
  }
  __syncthreads();

  int cur = 0;
  for (int m = 0; m < 16; ++m){
    // issue K loads for macro m+1 (own j-tile)
    bf16x8 fkN[4];
    if (m < 15){
      const u16* kpn = kp + 8192;
      #pragma unroll
      for (int oc = 0; oc < 4; oc++) fkN[oc] = ldb(kpn + oc * 512);
    }
    // PV over the 4 shared j-tiles of macro m
    #pragma unroll
    for (int jj = 0; jj < 4; jj++){
      bf16x8 pf0 = pfrag(cur, jj, 0);
      bf16x8 pf1 = pfrag(cur, jj, 1);
      bf16x8 fv00 = ldb(vp0 + (jj * 2 + 0) * 512);
      bf16x8 fv01 = ldb(vp0 + (jj * 2 + 1) * 512);
      bf16x8 fv10 = ldb(vp1 + (jj * 2 + 0) * 512);
      bf16x8 fv11 = ldb(vp1 + (jj * 2 + 1) * 512);
      acc0 = mfma32(fv00, pf0, acc0);
      acc0 = mfma32(fv01, pf1, acc0);
      acc1 = mfma32(fv10, pf0, acc1);
      acc1 = mfma32(fv11, pf1, acc1);
    }
    // S + P-write for macro m+1 into the other buffer
    if (m < 15) sphase(fkN, cur ^ 1);
    kp += 8192; vp0 += 4096; vp1 += 4096;
    __syncthreads();
    cur ^= 1;
  }

  // cross-wave l reduction: l(i) = sum over 4 waves' j-tile partials
  float l = (lacc[0] + lacc[1]) + (lacc[2] + lacc[3]);
  l = red_sum32(l);
  if (hi == 0) lredf[wv][li] = l;
  __syncthreads();
  float lfull = (lredf[0][li] + lredf[1][li]) + (lredf[2][li] + lredf[3][li]);

  float gm = gamma[0];
  float iv = 1.f / lfull;
  const float* xb = x + (size_t)b * C_ * W_;
  float* ob = out + (size_t)b * C_ * W_;
  int icol = i0 + li;
  #pragma unroll
  for (int t = 0; t < 16; t++){
    int crow = (t & 3) + 8 * (t >> 2) + 4 * hi;
    int c0 = cbase + crow, c1 = cbase + 32 + crow;
    ob[(size_t)c0 * W_ + icol] = gm * (acc0[t] * iv) + xb[(size_t)c0 * W_ + icol];
    ob[(size_t)c1 * W_ + icol] = gm * (acc1[t] * iv) + xb[(size_t)c1 * W_ + icol];
  }
}

extern "C" void kernel_launch(void* const* d_in, const int* in_sizes, int n_in,
                              void* d_out, int out_size, void* d_ws, size_t ws_size,
                              hipStream_t stream) {
  const float* x     = (const float*)d_in[0];
  const float* Wq    = (const float*)d_in[1];
  const float* bq    = (const float*)d_in[2];
  const float* Wk    = (const float*)d_in[3];
  const float* bk    = (const float*)d_in[4];
  const float* Wv    = (const float*)d_in[5];
  const float* bv    = (const float*)d_in[6];
  const float* gamma = (const float*)d_in[7];
  float* out = (float*)d_out;
  char* ws = (char*)d_ws;
  // workspace layout (~38.4 MB total)
  u16*   Wall = (u16*)  (ws + 0);         // 640*512*2        = 655360
  float* ball = (float*)(ws + 655360);    // 640*4            = 2560
  u16*   xbT  = (u16*)  (ws + 657920);    // 8*2048*512*2     = 16777216
  u16*   qf   = (u16*)  (ws + 17435136);  // 8*2048*64*2      = 2097152
  u16*   kf   = (u16*)  (ws + 19532288);  // 8*2048*64*2      = 2097152
  u16*   vf   = (u16*)  (ws + 21629440);  // 8*512*2048*2     = 16777216

  prep_w<<<dim3(1280), dim3(256), 0, stream>>>(Wq, bq, Wk, bk, Wv, bv, Wall, ball);
  xpose<<<dim3(64, 16, 8), dim3(256), 0, stream>>>(x, xbT);
  gemm_proj<<<dim3(32, 10, 8), dim3(256), 0, stream>>>(Wall, ball, xbT, qf, kf, vf);
  attn10<<<dim3(1024), dim3(256), 0, stream>>>(qf, kf, vf, x, gamma, out);
}

// Round 12
// 132.466 us; speedup vs baseline: 1.0741x; 1.0741x over previous
//
#include <hip/hip_runtime.h>
#include <stdint.h>

// Problem constants (SelfAttention: B=8, C=512, C8=64, W=2048)
#define B_  8
#define C_  512
#define CO_ 64
#define W_  2048
#define R_  640   // stacked projection rows: 64 q + 64 k + 512 v
#define LOG2E 1.4426950408889634f

typedef float f32x4 __attribute__((ext_vector_type(4)));
typedef float f32x16 __attribute__((ext_vector_type(16)));
typedef __bf16 bf16x8 __attribute__((ext_vector_type(8)));
typedef __bf16 bf16x2 __attribute__((ext_vector_type(2)));
typedef unsigned u32x2 __attribute__((ext_vector_type(2)));
typedef unsigned u32x4 __attribute__((ext_vector_type(4)));
typedef unsigned short u16;
typedef u16 u16x8 __attribute__((ext_vector_type(8)));
typedef u16 u16x4 __attribute__((ext_vector_type(4)));

static __device__ __forceinline__ float exp2g(float f){
  return __builtin_amdgcn_exp2f(f);    // v_exp_f32 (2^x)
}
static __device__ __forceinline__ u16 f2b(float f){
  union { float f; unsigned u; } v; v.f = f;
  unsigned r = v.u + 0x7FFFu + ((v.u >> 16) & 1u);  // RNE
  return (u16)(r >> 16);
}
static __device__ __forceinline__ bf16x8 ldb(const u16* p){
  return __builtin_bit_cast(bf16x8, *(const u16x8*)p);
}
static __device__ __forceinline__ f32x4 mfma16(bf16x8 a, bf16x8 b, f32x4 c){
  return __builtin_amdgcn_mfma_f32_16x16x32_bf16(a, b, c, 0, 0, 0);
}
static __device__ __forceinline__ f32x16 mfma32(bf16x8 a, bf16x8 b, f32x16 c){
  return __builtin_amdgcn_mfma_f32_32x32x16_bf16(a, b, c, 0, 0, 0);
}
// v_permlane32_swap_b32: vdst lanes[32:63] <-> vsrc lanes[0:31]
static __device__ __forceinline__ void pl32swap(unsigned &a, unsigned &b){
  asm("v_permlane32_swap_b32 %0, %1" : "+v"(a), "+v"(b));
}
static __device__ __forceinline__ float red_sum32(float v){
  unsigned a = __builtin_bit_cast(unsigned, v), b = a;
  pl32swap(a, b);
  return __builtin_bit_cast(float, a) + __builtin_bit_cast(float, b);
}
static __device__ __forceinline__ unsigned pkbf(float lo, float hi){
  bf16x2 t; t[0] = (__bf16)lo; t[1] = (__bf16)hi;
  return __builtin_bit_cast(unsigned, t);
}

// ---------------- K0: stack + cast weights/bias to bf16 ----------------
// Q rows are pre-scaled by log2(e) so attention softmax can use raw exp2.
__global__ __launch_bounds__(256) void prep_w(
    const float* __restrict__ Wq, const float* __restrict__ bq,
    const float* __restrict__ Wk, const float* __restrict__ bk,
    const float* __restrict__ Wv, const float* __restrict__ bv,
    u16* __restrict__ Wall, float* __restrict__ ball){
  int e = blockIdx.x * 256 + threadIdx.x;
  if (e < R_ * C_){
    int r = e >> 9, c = e & (C_ - 1);
    float w;
    if (r < 64)       w = Wq[r * C_ + c] * LOG2E;
    else if (r < 128) w = Wk[(r - 64) * C_ + c];
    else              w = Wv[(r - 128) * C_ + c];
    Wall[e] = f2b(w);
  }
  if (e < R_){
    float bb;
    if (e < 64)       bb = bq[e] * LOG2E;
    else if (e < 128) bb = bk[e - 64];
    else              bb = bv[e - 128];
    ball[e] = bb;
  }
}

// ---------------- K1: x [b][c][w] f32 -> xbT [b][w][c] bf16 ----------------
__global__ __launch_bounds__(256) void xpose(const float* __restrict__ x,
                                             u16* __restrict__ xbT){
  __shared__ float t[32][33];
  int b = blockIdx.z, c0 = blockIdx.y * 32, w0 = blockIdx.x * 32;
  int tx = threadIdx.x & 31, ty = threadIdx.x >> 5;   // ty 0..7
  const float* xb = x + (size_t)b * C_ * W_;
  #pragma unroll
  for (int k = 0; k < 4; k++)
    t[ty + k * 8][tx] = xb[(size_t)(c0 + ty + k * 8) * W_ + w0 + tx];
  __syncthreads();
  u16* ob = xbT + (size_t)b * W_ * C_;
  #pragma unroll
  for (int k = 0; k < 4; k++)
    ob[(size_t)(w0 + ty + k * 8) * C_ + c0 + tx] = f2b(t[tx][ty + k * 8]);
}

// ---------------- K2: fused projection GEMM ----------------
// Outputs stored FRAGMENT-MAJOR for the attention kernel's 32x32 MFMA:
//  Q/K: f[(w/32)][(o/16)][lane=((o>>3)&1)*32 + (w&31)][e=o&7]  (1KB/frag)
//  V:   f[(c/32)][(j/16)][lane=((j>>3)&1)*32 + (c&31)][e=j&7]  (1KB/frag)
#define PADW 40
__global__ __launch_bounds__(256) void gemm_proj(
    const u16* __restrict__ Wall, const float* __restrict__ ball,
    const u16* __restrict__ xbT, u16* __restrict__ qf,
    u16* __restrict__ kf, u16* __restrict__ vf){
  __shared__ u16 at[64][PADW];
  __shared__ u16 bt[64][PADW];
  int b = blockIdx.z;
  int m0 = blockIdx.y * 64, n0 = blockIdx.x * 64;
  int tid = threadIdx.x, lane = tid & 63, wid = tid >> 6;
  int wm = wid >> 1, wn = wid & 1;
  int g = lane >> 4, r = lane & 15;
  const u16* xb = xbT + (size_t)b * W_ * C_;
  f32x4 acc[2][2] = {};
  int srow = tid >> 2, sseg = (tid & 3) * 8;
  for (int kk = 0; kk < 16; kk++){
    int c0 = kk * 32;
    *(u16x8*)&at[srow][sseg] = *(const u16x8*)&Wall[(size_t)(m0 + srow) * C_ + c0 + sseg];
    *(u16x8*)&bt[srow][sseg] = *(const u16x8*)&xb[(size_t)(n0 + srow) * C_ + c0 + sseg];
    __syncthreads();
    bf16x8 a0 = ldb(&at[wm * 32 +  0 + r][g * 8]);
    bf16x8 a1 = ldb(&at[wm * 32 + 16 + r][g * 8]);
    bf16x8 b0 = ldb(&bt[wn * 32 +  0 + r][g * 8]);
    bf16x8 b1 = ldb(&bt[wn * 32 + 16 + r][g * 8]);
    acc[0][0] = mfma16(a0, b0, acc[0][0]);
    acc[0][1] = mfma16(a0, b1, acc[0][1]);
    acc[1][0] = mfma16(a1, b0, acc[1][0]);
    acc[1][1] = mfma16(a1, b1, acc[1][1]);
    __syncthreads();
  }
  // epilogue: bias + store fragment-major
  #pragma unroll
  for (int i = 0; i < 2; i++){
    #pragma unroll
    for (int n = 0; n < 2; n++){
      int rbase = m0 + wm * 32 + i * 16 + g * 4;       // stacked row (o or c+128)
      int wcol  = n0 + wn * 32 + n * 16 + r;           // w (i or j)
      if (m0 < 128){
        u16* base = (m0 == 0 ? qf : kf) + (size_t)b * W_ * CO_;
        int o0 = (rbase & 63);
        int oc = o0 >> 4, h2 = (o0 >> 3) & 1, e0 = o0 & 7;
        u16x4 pk;
        #pragma unroll
        for (int t = 0; t < 4; t++) pk[t] = f2b(acc[i][n][t] + ball[rbase + t]);
        *(u16x4*)&base[((size_t)((wcol >> 5) * 4 + oc) * 64 + h2 * 32 + (wcol & 31)) * 8 + e0] = pk;
      } else {
        u16* vb = vf + (size_t)b * C_ * W_;
        int jt = wcol >> 4, h2 = (wcol >> 3) & 1, e = wcol & 7;
        #pragma unroll
        for (int t = 0; t < 4; t++){
          int c = rbase + t - 128;
          vb[((size_t)((c >> 5) * (W_ / 16) + jt) * 64 + h2 * 32 + (c & 31)) * 8 + e] =
              f2b(acc[i][n][t] + ball[rbase + t]);
        }
      }
    }
  }
}

// ---------------- K3: P-shared flash attention v11 (deep V prefetch) ------
// Same structure as v10 (P-sharing, no-max exp2 softmax, XOR-swizzled LDS P)
// with the V fragment loads software-pipelined: fvB (jj2,3 of macro m) issues
// at macro top; fvA (jj0,1 of macro m+1) issues mid-macro. Every global load
// now has >=350cy of cover. (256,3): ~12 waves/CU, no spill (~160 live regs).
__global__ __launch_bounds__(256, 3) void attn11(
    const u16* __restrict__ qf, const u16* __restrict__ kf,
    const u16* __restrict__ vf, const float* __restrict__ x,
    const float* __restrict__ gamma, float* __restrict__ out){
  __shared__ u16 pb[2][32][132];      // P double buffer, [i][j(swizzled)]
  __shared__ float lredf[4][32];      // per-wave row-sum partials
  int tid = threadIdx.x, lane = tid & 63, wv = tid >> 6;
  int bid = blockIdx.x;
  int b = bid & 7;
  int u = bid >> 3;                    // 0..127
  int i0 = (u & 63) * 32;
  int cbase = (u >> 6) * 256 + wv * 64;
  int li = lane & 31, hi = lane >> 5;
  int swz = (li & 7) << 3;             // XOR key, bits 3..5 of j
  const u16* qfb = qf + (size_t)b * W_ * CO_;
  const u16* kfb = kf + (size_t)b * W_ * CO_;
  const u16* vfb = vf + (size_t)b * C_ * W_;

  // Q B-frags: qf[(i0/32)][oc][lane][8]
  bf16x8 fq[4];
  {
    const u16* qp = &qfb[(size_t)(i0 >> 5) * 4 * 512 + lane * 8];
    #pragma unroll
    for (int oc = 0; oc < 4; oc++) fq[oc] = ldb(qp + oc * 512);
  }

  // streaming bases: K for this wave's own j-tiles (4m+wv); V for c-slice
  const u16* kp = &kfb[(size_t)wv * 2048 + lane * 8];   // += 8192 per macro
  const u16* vp0 = &vfb[(size_t)(cbase >> 5) * (W_ / 16) * 512 + lane * 8];
  const u16* vp1 = vp0 + (size_t)(W_ / 16) * 512;       // += 4096 per macro

  f32x16 acc0 = {}, acc1 = {};
  f32x4 lacc = {};

  // softmax + P-write for one j-tile from fk, into buffer bsel
  auto sphase = [&](bf16x8 (&fk)[4], int bsel){
    f32x16 S = {};
    S = mfma32(fk[0], fq[0], S);
    S = mfma32(fk[1], fq[1], S);
    S = mfma32(fk[2], fq[2], S);
    S = mfma32(fk[3], fq[3], S);
    float p[16];
    #pragma unroll
    for (int t = 0; t < 16; t++) p[t] = exp2g(S[t]);
    #pragma unroll
    for (int t = 0; t < 4; t++)
      lacc[t] += ((p[t] + p[4 + t]) + (p[8 + t] + p[12 + t]));
    // write 4x b64: p[4B..4B+3] -> j = wv*32 + 8*B + 4*hi (+swizzle)
    #pragma unroll
    for (int B = 0; B < 4; B++){
      unsigned lo = pkbf(p[4 * B + 0], p[4 * B + 1]);
      unsigned h2 = pkbf(p[4 * B + 2], p[4 * B + 3]);
      int j0 = (wv * 32 + 8 * B + 4 * hi) ^ swz;
      u32x2 wpair = {lo, h2};
      *(u32x2*)&pb[bsel][li][j0] = wpair;
    }
  };
  // read P B-frag for (j-tile jj, K-chunk kj) from buffer bsel
  auto pfrag = [&](int bsel, int jj, int kj) -> bf16x8 {
    int j0 = (jj * 32 + kj * 16 + 8 * hi) ^ swz;
    u16x4 a = *(const u16x4*)&pb[bsel][li][j0];
    u16x4 c = *(const u16x4*)&pb[bsel][li][j0 + 4];
    u16x8 w = {a[0], a[1], a[2], a[3], c[0], c[1], c[2], c[3]};
    return __builtin_bit_cast(bf16x8, w);
  };

  // prologue: S(macro 0) -> buf 0; V frags for macro 0 jj0,1 in flight
  bf16x8 fvA0, fvA1, fvA2, fvA3, fvA4, fvA5, fvA6, fvA7;
  {
    bf16x8 fk[4];
    #pragma unroll
    for (int oc = 0; oc < 4; oc++) fk[oc] = ldb(kp + oc * 512);
    sphase(fk, 0);
  }
  // jj0: {vp0,vp0+512, vp1,vp1+512}; jj1: {vp0+1024,+1536, vp1+1024,+1536}
  fvA0 = ldb(vp0);        fvA1 = ldb(vp0 + 512);
  fvA2 = ldb(vp1);        fvA3 = ldb(vp1 + 512);
  fvA4 = ldb(vp0 + 1024); fvA5 = ldb(vp0 + 1536);
  fvA6 = ldb(vp1 + 1024); fvA7 = ldb(vp1 + 1536);
  __syncthreads();

  int cur = 0;
  for (int m = 0; m < 16; ++m){
    // K loads for macro m+1 (own j-tile) — consumed in sphase at macro end
    bf16x8 fkN[4];
    if (m < 15){
      const u16* kpn = kp + 8192;
      #pragma unroll
      for (int oc = 0; oc < 4; oc++) fkN[oc] = ldb(kpn + oc * 512);
    }
    // V frags for jj2,3 of THIS macro — consumed ~350cy later
    bf16x8 fvB0 = ldb(vp0 + 2048), fvB1 = ldb(vp0 + 2560);
    bf16x8 fvB2 = ldb(vp1 + 2048), fvB3 = ldb(vp1 + 2560);
    bf16x8 fvB4 = ldb(vp0 + 3072), fvB5 = ldb(vp0 + 3584);
    bf16x8 fvB6 = ldb(vp1 + 3072), fvB7 = ldb(vp1 + 3584);
    // jj0 (fvA0..3)
    {
      bf16x8 pf0 = pfrag(cur, 0, 0), pf1 = pfrag(cur, 0, 1);
      acc0 = mfma32(fvA0, pf0, acc0); acc0 = mfma32(fvA1, pf1, acc0);
      acc1 = mfma32(fvA2, pf0, acc1); acc1 = mfma32(fvA3, pf1, acc1);
    }
    // jj1 (fvA4..7)
    {
      bf16x8 pf0 = pfrag(cur, 1, 0), pf1 = pfrag(cur, 1, 1);
      acc0 = mfma32(fvA4, pf0, acc0); acc0 = mfma32(fvA5, pf1, acc0);
      acc1 = mfma32(fvA6, pf0, acc1); acc1 = mfma32(fvA7, pf1, acc1);
    }
    // V frags for jj0,1 of macro m+1 — consumed after the barrier
    if (m < 15){
      fvA0 = ldb(vp0 + 4096); fvA1 = ldb(vp0 + 4608);
      fvA2 = ldb(vp1 + 4096); fvA3 = ldb(vp1 + 4608);
      fvA4 = ldb(vp0 + 5120); fvA5 = ldb(vp0 + 5632);
      fvA6 = ldb(vp1 + 5120); fvA7 = ldb(vp1 + 5632);
    }
    // jj2 (fvB0..3)
    {
      bf16x8 pf0 = pfrag(cur, 2, 0), pf1 = pfrag(cur, 2, 1);
      acc0 = mfma32(fvB0, pf0, acc0); acc0 = mfma32(fvB1, pf1, acc0);
      acc1 = mfma32(fvB2, pf0, acc1); acc1 = mfma32(fvB3, pf1, acc1);
    }
    // jj3 (fvB4..7)
    {
      bf16x8 pf0 = pfrag(cur, 3, 0), pf1 = pfrag(cur, 3, 1);
      acc0 = mfma32(fvB4, pf0, acc0); acc0 = mfma32(fvB5, pf1, acc0);
      acc1 = mfma32(fvB6, pf0, acc1); acc1 = mfma32(fvB7, pf1, acc1);
    }
    // S + P-write for macro m+1 into the other buffer
    if (m < 15) sphase(fkN, cur ^ 1);
    kp += 8192; vp0 += 4096; vp1 += 4096;
    __syncthreads();
    cur ^= 1;
  }

  // cross-wave l reduction: l(i) = sum over 4 waves' j-tile partials
  float l = (lacc[0] + lacc[1]) + (lacc[2] + lacc[3]);
  l = red_sum32(l);
  if (hi == 0) lredf[wv][li] = l;
  __syncthreads();
  float lfull = (lredf[0][li] + lredf[1][li]) + (lredf[2][li] + lredf[3][li]);

  float gm = gamma[0];
  float iv = 1.f / lfull;
  const float* xb = x + (size_t)b * C_ * W_;
  float* ob = out + (size_t)b * C_ * W_;
  int icol = i0 + li;
  #pragma unroll
  for (int t = 0; t < 16; t++){
    int crow = (t & 3) + 8 * (t >> 2) + 4 * hi;
    int c0 = cbase + crow, c1 = cbase + 32 + crow;
    ob[(size_t)c0 * W_ + icol] = gm * (acc0[t] * iv) + xb[(size_t)c0 * W_ + icol];
    ob[(size_t)c1 * W_ + icol] = gm * (acc1[t] * iv) + xb[(size_t)c1 * W_ + icol];
  }
}

extern "C" void kernel_launch(void* const* d_in, const int* in_sizes, int n_in,
                              void* d_out, int out_size, void* d_ws, size_t ws_size,
                              hipStream_t stream) {
  const float* x     = (const float*)d_in[0];
  const float* Wq    = (const float*)d_in[1];
  const float* bq    = (const float*)d_in[2];
  const float* Wk    = (const float*)d_in[3];
  const float* bk    = (const float*)d_in[4];
  const float* Wv    = (const float*)d_in[5];
  const float* bv    = (const float*)d_in[6];
  const float* gamma = (const float*)d_in[7];
  float* out = (float*)d_out;
  char* ws = (char*)d_ws;
  // workspace layout (~38.4 MB total)
  u16*   Wall = (u16*)  (ws + 0);         // 640*512*2        = 655360
  float* ball = (float*)(ws + 655360);    // 640*4            = 2560
  u16*   xbT  = (u16*)  (ws + 657920);    // 8*2048*512*2     = 16777216
  u16*   qf   = (u16*)  (ws + 17435136);  // 8*2048*64*2      = 2097152
  u16*   kf   = (u16*)  (ws + 19532288);  // 8*2048*64*2      = 2097152
  u16*   vf   = (u16*)  (ws + 21629440);  // 8*512*2048*2     = 16777216

  prep_w<<<dim3(1280), dim3(256), 0, stream>>>(Wq, bq, Wk, bk, Wv, bv, Wall, ball);
  xpose<<<dim3(64, 16, 8), dim3(256), 0, stream>>>(x, xbT);
  gemm_proj<<<dim3(32, 10, 8), dim3(256), 0, stream>>>(Wall, ball, xbT, qf, kf, vf);
  attn11<<<dim3(1024), dim3(256), 0, stream>>>(qf, kf, vf, x, gamma, out);
}

// Round 13
// 108.853 us; speedup vs baseline: 1.3071x; 1.2169x over previous
//
#include <hip/hip_runtime.h>
#include <stdint.h>

// Problem constants (SelfAttention: B=8, C=512, C8=64, W=2048)
#define B_  8
#define C_  512
#define CO_ 64
#define W_  2048
#define R_  640   // stacked projection rows: 64 q + 64 k + 512 v
#define LOG2E 1.4426950408889634f

typedef float f32x4 __attribute__((ext_vector_type(4)));
typedef float f32x16 __attribute__((ext_vector_type(16)));
typedef __bf16 bf16x8 __attribute__((ext_vector_type(8)));
typedef __bf16 bf16x2 __attribute__((ext_vector_type(2)));
typedef unsigned u32x2 __attribute__((ext_vector_type(2)));
typedef unsigned u32x4 __attribute__((ext_vector_type(4)));
typedef unsigned short u16;
typedef u16 u16x8 __attribute__((ext_vector_type(8)));
typedef u16 u16x4 __attribute__((ext_vector_type(4)));

static __device__ __forceinline__ float exp2g(float f){
  return __builtin_amdgcn_exp2f(f);    // v_exp_f32 (2^x)
}
static __device__ __forceinline__ u16 f2b(float f){
  union { float f; unsigned u; } v; v.f = f;
  unsigned r = v.u + 0x7FFFu + ((v.u >> 16) & 1u);  // RNE
  return (u16)(r >> 16);
}
static __device__ __forceinline__ bf16x8 ldb(const u16* p){
  return __builtin_bit_cast(bf16x8, *(const u16x8*)p);
}
static __device__ __forceinline__ f32x4 mfma16(bf16x8 a, bf16x8 b, f32x4 c){
  return __builtin_amdgcn_mfma_f32_16x16x32_bf16(a, b, c, 0, 0, 0);
}
static __device__ __forceinline__ f32x16 mfma32(bf16x8 a, bf16x8 b, f32x16 c){
  return __builtin_amdgcn_mfma_f32_32x32x16_bf16(a, b, c, 0, 0, 0);
}
// v_permlane32_swap_b32: vdst lanes[32:63] <-> vsrc lanes[0:31]
static __device__ __forceinline__ void pl32swap(unsigned &a, unsigned &b){
  asm("v_permlane32_swap_b32 %0, %1" : "+v"(a), "+v"(b));
}
static __device__ __forceinline__ float red_sum32(float v){
  unsigned a = __builtin_bit_cast(unsigned, v), b = a;
  pl32swap(a, b);
  return __builtin_bit_cast(float, a) + __builtin_bit_cast(float, b);
}
static __device__ __forceinline__ unsigned pkbf(float lo, float hi){
  bf16x2 t; t[0] = (__bf16)lo; t[1] = (__bf16)hi;
  return __builtin_bit_cast(unsigned, t);
}
// raw barrier: drain ONLY LDS (lgkmcnt); VMEM prefetches stay in flight
static __device__ __forceinline__ void barrier_lds_only(){
  asm volatile("s_waitcnt lgkmcnt(0)" ::: "memory");
  __builtin_amdgcn_s_barrier();
}

// ---------------- K0: stack + cast weights/bias to bf16 ----------------
// Q rows are pre-scaled by log2(e) so attention softmax can use raw exp2.
__global__ __launch_bounds__(256) void prep_w(
    const float* __restrict__ Wq, const float* __restrict__ bq,
    const float* __restrict__ Wk, const float* __restrict__ bk,
    const float* __restrict__ Wv, const float* __restrict__ bv,
    u16* __restrict__ Wall, float* __restrict__ ball){
  int e = blockIdx.x * 256 + threadIdx.x;
  if (e < R_ * C_){
    int r = e >> 9, c = e & (C_ - 1);
    float w;
    if (r < 64)       w = Wq[r * C_ + c] * LOG2E;
    else if (r < 128) w = Wk[(r - 64) * C_ + c];
    else              w = Wv[(r - 128) * C_ + c];
    Wall[e] = f2b(w);
  }
  if (e < R_){
    float bb;
    if (e < 64)       bb = bq[e] * LOG2E;
    else if (e < 128) bb = bk[e - 64];
    else              bb = bv[e - 128];
    ball[e] = bb;
  }
}

// ---------------- K1: x [b][c][w] f32 -> xbT [b][w][c] bf16 ----------------
__global__ __launch_bounds__(256) void xpose(const float* __restrict__ x,
                                             u16* __restrict__ xbT){
  __shared__ float t[32][33];
  int b = blockIdx.z, c0 = blockIdx.y * 32, w0 = blockIdx.x * 32;
  int tx = threadIdx.x & 31, ty = threadIdx.x >> 5;   // ty 0..7
  const float* xb = x + (size_t)b * C_ * W_;
  #pragma unroll
  for (int k = 0; k < 4; k++)
    t[ty + k * 8][tx] = xb[(size_t)(c0 + ty + k * 8) * W_ + w0 + tx];
  __syncthreads();
  u16* ob = xbT + (size_t)b * W_ * C_;
  #pragma unroll
  for (int k = 0; k < 4; k++)
    ob[(size_t)(w0 + ty + k * 8) * C_ + c0 + tx] = f2b(t[tx][ty + k * 8]);
}

// ---------------- K2: fused projection GEMM ----------------
// Outputs stored FRAGMENT-MAJOR for the attention kernel's 32x32 MFMA:
//  Q/K: f[(w/32)][(o/16)][lane=((o>>3)&1)*32 + (w&31)][e=o&7]  (1KB/frag)
//  V:   f[(c/32)][(j/16)][lane=((j>>3)&1)*32 + (c&31)][e=j&7]  (1KB/frag)
#define PADW 40
__global__ __launch_bounds__(256) void gemm_proj(
    const u16* __restrict__ Wall, const float* __restrict__ ball,
    const u16* __restrict__ xbT, u16* __restrict__ qf,
    u16* __restrict__ kf, u16* __restrict__ vf){
  __shared__ u16 at[64][PADW];
  __shared__ u16 bt[64][PADW];
  int b = blockIdx.z;
  int m0 = blockIdx.y * 64, n0 = blockIdx.x * 64;
  int tid = threadIdx.x, lane = tid & 63, wid = tid >> 6;
  int wm = wid >> 1, wn = wid & 1;
  int g = lane >> 4, r = lane & 15;
  const u16* xb = xbT + (size_t)b * W_ * C_;
  f32x4 acc[2][2] = {};
  int srow = tid >> 2, sseg = (tid & 3) * 8;
  for (int kk = 0; kk < 16; kk++){
    int c0 = kk * 32;
    *(u16x8*)&at[srow][sseg] = *(const u16x8*)&Wall[(size_t)(m0 + srow) * C_ + c0 + sseg];
    *(u16x8*)&bt[srow][sseg] = *(const u16x8*)&xb[(size_t)(n0 + srow) * C_ + c0 + sseg];
    __syncthreads();
    bf16x8 a0 = ldb(&at[wm * 32 +  0 + r][g * 8]);
    bf16x8 a1 = ldb(&at[wm * 32 + 16 + r][g * 8]);
    bf16x8 b0 = ldb(&bt[wn * 32 +  0 + r][g * 8]);
    bf16x8 b1 = ldb(&bt[wn * 32 + 16 + r][g * 8]);
    acc[0][0] = mfma16(a0, b0, acc[0][0]);
    acc[0][1] = mfma16(a0, b1, acc[0][1]);
    acc[1][0] = mfma16(a1, b0, acc[1][0]);
    acc[1][1] = mfma16(a1, b1, acc[1][1]);
    __syncthreads();
  }
  // epilogue: bias + store fragment-major
  #pragma unroll
  for (int i = 0; i < 2; i++){
    #pragma unroll
    for (int n = 0; n < 2; n++){
      int rbase = m0 + wm * 32 + i * 16 + g * 4;       // stacked row (o or c+128)
      int wcol  = n0 + wn * 32 + n * 16 + r;           // w (i or j)
      if (m0 < 128){
        u16* base = (m0 == 0 ? qf : kf) + (size_t)b * W_ * CO_;
        int o0 = (rbase & 63);
        int oc = o0 >> 4, h2 = (o0 >> 3) & 1, e0 = o0 & 7;
        u16x4 pk;
        #pragma unroll
        for (int t = 0; t < 4; t++) pk[t] = f2b(acc[i][n][t] + ball[rbase + t]);
        *(u16x4*)&base[((size_t)((wcol >> 5) * 4 + oc) * 64 + h2 * 32 + (wcol & 31)) * 8 + e0] = pk;
      } else {
        u16* vb = vf + (size_t)b * C_ * W_;
        int jt = wcol >> 4, h2 = (wcol >> 3) & 1, e = wcol & 7;
        #pragma unroll
        for (int t = 0; t < 4; t++){
          int c = rbase + t - 128;
          vb[((size_t)((c >> 5) * (W_ / 16) + jt) * 64 + h2 * 32 + (c & 31)) * 8 + e] =
              f2b(acc[i][n][t] + ball[rbase + t]);
        }
      }
    }
  }
}

// ---------------- K3: P-shared flash attention v12 (raw barriers) ---------
// v11 structure (P-sharing, no-max exp2 softmax, deep V prefetch) with the
// per-macro __syncthreads() replaced by lgkmcnt(0)+s_barrier: VMEM prefetches
// (fkN, fvA/fvB) are NOT drained at the barrier (T3/T4) — they stay in
// flight and are consumed under compiler-counted vmcnt. T5 setprio on PV.
__global__ __launch_bounds__(256, 3) void attn12(
    const u16* __restrict__ qf, const u16* __restrict__ kf,
    const u16* __restrict__ vf, const float* __restrict__ x,
    const float* __restrict__ gamma, float* __restrict__ out){
  __shared__ u16 pb[2][32][132];      // P double buffer, [i][j(swizzled)]
  __shared__ float lredf[4][32];      // per-wave row-sum partials
  int tid = threadIdx.x, lane = tid & 63, wv = tid >> 6;
  int bid = blockIdx.x;
  int b = bid & 7;
  int u = bid >> 3;                    // 0..127
  int i0 = (u & 63) * 32;
  int cbase = (u >> 6) * 256 + wv * 64;
  int li = lane & 31, hi = lane >> 5;
  int swz = (li & 7) << 3;             // XOR key, bits 3..5 of j
  const u16* qfb = qf + (size_t)b * W_ * CO_;
  const u16* kfb = kf + (size_t)b * W_ * CO_;
  const u16* vfb = vf + (size_t)b * C_ * W_;

  // Q B-frags: qf[(i0/32)][oc][lane][8]
  bf16x8 fq[4];
  {
    const u16* qp = &qfb[(size_t)(i0 >> 5) * 4 * 512 + lane * 8];
    #pragma unroll
    for (int oc = 0; oc < 4; oc++) fq[oc] = ldb(qp + oc * 512);
  }

  // streaming bases: K for this wave's own j-tiles (4m+wv); V for c-slice
  const u16* kp = &kfb[(size_t)wv * 2048 + lane * 8];   // += 8192 per macro
  const u16* vp0 = &vfb[(size_t)(cbase >> 5) * (W_ / 16) * 512 + lane * 8];
  const u16* vp1 = vp0 + (size_t)(W_ / 16) * 512;       // += 4096 per macro

  f32x16 acc0 = {}, acc1 = {};
  f32x4 lacc = {};

  // softmax + P-write for one j-tile from fk, into buffer bsel
  auto sphase = [&](bf16x8 (&fk)[4], int bsel){
    f32x16 S = {};
    S = mfma32(fk[0], fq[0], S);
    S = mfma32(fk[1], fq[1], S);
    S = mfma32(fk[2], fq[2], S);
    S = mfma32(fk[3], fq[3], S);
    float p[16];
    #pragma unroll
    for (int t = 0; t < 16; t++) p[t] = exp2g(S[t]);
    #pragma unroll
    for (int t = 0; t < 4; t++)
      lacc[t] += ((p[t] + p[4 + t]) + (p[8 + t] + p[12 + t]));
    // write 4x b64: p[4B..4B+3] -> j = wv*32 + 8*B + 4*hi (+swizzle)
    #pragma unroll
    for (int B = 0; B < 4; B++){
      unsigned lo = pkbf(p[4 * B + 0], p[4 * B + 1]);
      unsigned h2 = pkbf(p[4 * B + 2], p[4 * B + 3]);
      int j0 = (wv * 32 + 8 * B + 4 * hi) ^ swz;
      u32x2 wpair = {lo, h2};
      *(u32x2*)&pb[bsel][li][j0] = wpair;
    }
  };
  // read P B-frag for (j-tile jj, K-chunk kj) from buffer bsel
  auto pfrag = [&](int bsel, int jj, int kj) -> bf16x8 {
    int j0 = (jj * 32 + kj * 16 + 8 * hi) ^ swz;
    u16x4 a = *(const u16x4*)&pb[bsel][li][j0];
    u16x4 c = *(const u16x4*)&pb[bsel][li][j0 + 4];
    u16x8 w = {a[0], a[1], a[2], a[3], c[0], c[1], c[2], c[3]};
    return __builtin_bit_cast(bf16x8, w);
  };

  // prologue: S(macro 0) -> buf 0; V frags for macro 0 jj0,1 in flight
  bf16x8 fvA0, fvA1, fvA2, fvA3, fvA4, fvA5, fvA6, fvA7;
  {
    bf16x8 fk[4];
    #pragma unroll
    for (int oc = 0; oc < 4; oc++) fk[oc] = ldb(kp + oc * 512);
    sphase(fk, 0);
  }
  // jj0: {vp0,vp0+512, vp1,vp1+512}; jj1: {vp0+1024,+1536, vp1+1024,+1536}
  fvA0 = ldb(vp0);        fvA1 = ldb(vp0 + 512);
  fvA2 = ldb(vp1);        fvA3 = ldb(vp1 + 512);
  fvA4 = ldb(vp0 + 1024); fvA5 = ldb(vp0 + 1536);
  fvA6 = ldb(vp1 + 1024); fvA7 = ldb(vp1 + 1536);
  barrier_lds_only();

  int cur = 0;
  for (int m = 0; m < 16; ++m){
    // K loads for macro m+1 (own j-tile) — consumed in sphase at macro end
    bf16x8 fkN[4];
    if (m < 15){
      const u16* kpn = kp + 8192;
      #pragma unroll
      for (int oc = 0; oc < 4; oc++) fkN[oc] = ldb(kpn + oc * 512);
    }
    // V frags for jj2,3 of THIS macro — consumed ~350cy later
    bf16x8 fvB0 = ldb(vp0 + 2048), fvB1 = ldb(vp0 + 2560);
    bf16x8 fvB2 = ldb(vp1 + 2048), fvB3 = ldb(vp1 + 2560);
    bf16x8 fvB4 = ldb(vp0 + 3072), fvB5 = ldb(vp0 + 3584);
    bf16x8 fvB6 = ldb(vp1 + 3072), fvB7 = ldb(vp1 + 3584);
    // jj0 (fvA0..3)
    {
      bf16x8 pf0 = pfrag(cur, 0, 0), pf1 = pfrag(cur, 0, 1);
      __builtin_amdgcn_s_setprio(1);
      acc0 = mfma32(fvA0, pf0, acc0); acc0 = mfma32(fvA1, pf1, acc0);
      acc1 = mfma32(fvA2, pf0, acc1); acc1 = mfma32(fvA3, pf1, acc1);
      __builtin_amdgcn_s_setprio(0);
    }
    // jj1 (fvA4..7)
    {
      bf16x8 pf0 = pfrag(cur, 1, 0), pf1 = pfrag(cur, 1, 1);
      __builtin_amdgcn_s_setprio(1);
      acc0 = mfma32(fvA4, pf0, acc0); acc0 = mfma32(fvA5, pf1, acc0);
      acc1 = mfma32(fvA6, pf0, acc1); acc1 = mfma32(fvA7, pf1, acc1);
      __builtin_amdgcn_s_setprio(0);
    }
    // V frags for jj0,1 of macro m+1 — consumed after the barrier
    if (m < 15){
      fvA0 = ldb(vp0 + 4096); fvA1 = ldb(vp0 + 4608);
      fvA2 = ldb(vp1 + 4096); fvA3 = ldb(vp1 + 4608);
      fvA4 = ldb(vp0 + 5120); fvA5 = ldb(vp0 + 5632);
      fvA6 = ldb(vp1 + 5120); fvA7 = ldb(vp1 + 5632);
    }
    // jj2 (fvB0..3)
    {
      bf16x8 pf0 = pfrag(cur, 2, 0), pf1 = pfrag(cur, 2, 1);
      __builtin_amdgcn_s_setprio(1);
      acc0 = mfma32(fvB0, pf0, acc0); acc0 = mfma32(fvB1, pf1, acc0);
      acc1 = mfma32(fvB2, pf0, acc1); acc1 = mfma32(fvB3, pf1, acc1);
      __builtin_amdgcn_s_setprio(0);
    }
    // jj3 (fvB4..7)
    {
      bf16x8 pf0 = pfrag(cur, 3, 0), pf1 = pfrag(cur, 3, 1);
      __builtin_amdgcn_s_setprio(1);
      acc0 = mfma32(fvB4, pf0, acc0); acc0 = mfma32(fvB5, pf1, acc0);
      acc1 = mfma32(fvB6, pf0, acc1); acc1 = mfma32(fvB7, pf1, acc1);
      __builtin_amdgcn_s_setprio(0);
    }
    // S + P-write for macro m+1 into the other buffer
    if (m < 15) sphase(fkN, cur ^ 1);
    kp += 8192; vp0 += 4096; vp1 += 4096;
    // raw barrier: LDS drained, VMEM prefetches stay in flight (T3/T4)
    barrier_lds_only();
    cur ^= 1;
  }

  // cross-wave l reduction: l(i) = sum over 4 waves' j-tile partials
  float l = (lacc[0] + lacc[1]) + (lacc[2] + lacc[3]);
  l = red_sum32(l);
  if (hi == 0) lredf[wv][li] = l;
  __syncthreads();
  float lfull = (lredf[0][li] + lredf[1][li]) + (lredf[2][li] + lredf[3][li]);

  float gm = gamma[0];
  float iv = 1.f / lfull;
  const float* xb = x + (size_t)b * C_ * W_;
  float* ob = out + (size_t)b * C_ * W_;
  int icol = i0 + li;
  #pragma unroll
  for (int t = 0; t < 16; t++){
    int crow = (t & 3) + 8 * (t >> 2) + 4 * hi;
    int c0 = cbase + crow, c1 = cbase + 32 + crow;
    ob[(size_t)c0 * W_ + icol] = gm * (acc0[t] * iv) + xb[(size_t)c0 * W_ + icol];
    ob[(size_t)c1 * W_ + icol] = gm * (acc1[t] * iv) + xb[(size_t)c1 * W_ + icol];
  }
}

extern "C" void kernel_launch(void* const* d_in, const int* in_sizes, int n_in,
                              void* d_out, int out_size, void* d_ws, size_t ws_size,
                              hipStream_t stream) {
  const float* x     = (const float*)d_in[0];
  const float* Wq    = (const float*)d_in[1];
  const float* bq    = (const float*)d_in[2];
  const float* Wk    = (const float*)d_in[3];
  const float* bk    = (const float*)d_in[4];
  const float* Wv    = (const float*)d_in[5];
  const float* bv    = (const float*)d_in[6];
  const float* gamma = (const float*)d_in[7];
  float* out = (float*)d_out;
  char* ws = (char*)d_ws;
  // workspace layout (~38.4 MB total)
  u16*   Wall = (u16*)  (ws + 0);         // 640*512*2        = 655360
  float* ball = (float*)(ws + 655360);    // 640*4            = 2560
  u16*   xbT  = (u16*)  (ws + 657920);    // 8*2048*512*2     = 16777216
  u16*   qf   = (u16*)  (ws + 17435136);  // 8*2048*64*2      = 2097152
  u16*   kf   = (u16*)  (ws + 19532288);  // 8*2048*64*2      = 2097152
  u16*   vf   = (u16*)  (ws + 21629440);  // 8*512*2048*2     = 16777216

  prep_w<<<dim3(1280), dim3(256), 0, stream>>>(Wq, bq, Wk, bk, Wv, bv, Wall, ball);
  xpose<<<dim3(64, 16, 8), dim3(256), 0, stream>>>(x, xbT);
  gemm_proj<<<dim3(32, 10, 8), dim3(256), 0, stream>>>(Wall, ball, xbT, qf, kf, vf);
  attn12<<<dim3(1024), dim3(256), 0, stream>>>(qf, kf, vf, x, gamma, out);
}

// Round 14
// 103.187 us; speedup vs baseline: 1.3788x; 1.0549x over previous
//
#include <hip/hip_runtime.h>
#include <stdint.h>

// Problem constants (SelfAttention: B=8, C=512, C8=64, W=2048)
#define B_  8
#define C_  512
#define CO_ 64
#define W_  2048
#define R_  640   // stacked projection rows: 64 q + 64 k + 512 v
#define LOG2E 1.4426950408889634f

typedef float f32x4 __attribute__((ext_vector_type(4)));
typedef float f32x16 __attribute__((ext_vector_type(16)));
typedef __bf16 bf16x8 __attribute__((ext_vector_type(8)));
typedef __bf16 bf16x2 __attribute__((ext_vector_type(2)));
typedef unsigned u32x2 __attribute__((ext_vector_type(2)));
typedef unsigned u32x4 __attribute__((ext_vector_type(4)));
typedef unsigned short u16;
typedef u16 u16x8 __attribute__((ext_vector_type(8)));
typedef u16 u16x4 __attribute__((ext_vector_type(4)));

static __device__ __forceinline__ float exp2g(float f){
  return __builtin_amdgcn_exp2f(f);    // v_exp_f32 (2^x)
}
static __device__ __forceinline__ u16 f2b(float f){
  union { float f; unsigned u; } v; v.f = f;
  unsigned r = v.u + 0x7FFFu + ((v.u >> 16) & 1u);  // RNE
  return (u16)(r >> 16);
}
static __device__ __forceinline__ bf16x8 ldb(const u16* p){
  return __builtin_bit_cast(bf16x8, *(const u16x8*)p);
}
static __device__ __forceinline__ f32x4 mfma16(bf16x8 a, bf16x8 b, f32x4 c){
  return __builtin_amdgcn_mfma_f32_16x16x32_bf16(a, b, c, 0, 0, 0);
}
static __device__ __forceinline__ f32x16 mfma32(bf16x8 a, bf16x8 b, f32x16 c){
  return __builtin_amdgcn_mfma_f32_32x32x16_bf16(a, b, c, 0, 0, 0);
}
// v_permlane32_swap_b32: vdst lanes[32:63] <-> vsrc lanes[0:31]
static __device__ __forceinline__ void pl32swap(unsigned &a, unsigned &b){
  asm("v_permlane32_swap_b32 %0, %1" : "+v"(a), "+v"(b));
}
static __device__ __forceinline__ float red_sum32(float v){
  unsigned a = __builtin_bit_cast(unsigned, v), b = a;
  pl32swap(a, b);
  return __builtin_bit_cast(float, a) + __builtin_bit_cast(float, b);
}
static __device__ __forceinline__ unsigned pkbf(float lo, float hi){
  bf16x2 t; t[0] = (__bf16)lo; t[1] = (__bf16)hi;
  return __builtin_bit_cast(unsigned, t);
}
// raw barrier: drain ONLY LDS (lgkmcnt); VMEM prefetches stay in flight
static __device__ __forceinline__ void barrier_lds_only(){
  asm volatile("s_waitcnt lgkmcnt(0)" ::: "memory");
  __builtin_amdgcn_s_barrier();
}

// ---------------- K0: stack + cast weights/bias to bf16 ----------------
// Q rows are pre-scaled by log2(e) so attention softmax can use raw exp2.
__global__ __launch_bounds__(256) void prep_w(
    const float* __restrict__ Wq, const float* __restrict__ bq,
    const float* __restrict__ Wk, const float* __restrict__ bk,
    const float* __restrict__ Wv, const float* __restrict__ bv,
    u16* __restrict__ Wall, float* __restrict__ ball){
  int e = blockIdx.x * 256 + threadIdx.x;
  if (e < R_ * C_){
    int r = e >> 9, c = e & (C_ - 1);
    float w;
    if (r < 64)       w = Wq[r * C_ + c] * LOG2E;
    else if (r < 128) w = Wk[(r - 64) * C_ + c];
    else              w = Wv[(r - 128) * C_ + c];
    Wall[e] = f2b(w);
  }
  if (e < R_){
    float bb;
    if (e < 64)       bb = bq[e] * LOG2E;
    else if (e < 128) bb = bk[e - 64];
    else              bb = bv[e - 128];
    ball[e] = bb;
  }
}

// ---------------- K1: x [b][c][w] f32 -> xbT [b][w][c] bf16 ----------------
__global__ __launch_bounds__(256) void xpose(const float* __restrict__ x,
                                             u16* __restrict__ xbT){
  __shared__ float t[32][33];
  int b = blockIdx.z, c0 = blockIdx.y * 32, w0 = blockIdx.x * 32;
  int tx = threadIdx.x & 31, ty = threadIdx.x >> 5;   // ty 0..7
  const float* xb = x + (size_t)b * C_ * W_;
  #pragma unroll
  for (int k = 0; k < 4; k++)
    t[ty + k * 8][tx] = xb[(size_t)(c0 + ty + k * 8) * W_ + w0 + tx];
  __syncthreads();
  u16* ob = xbT + (size_t)b * W_ * C_;
  #pragma unroll
  for (int k = 0; k < 4; k++)
    ob[(size_t)(w0 + ty + k * 8) * C_ + c0 + tx] = f2b(t[tx][ty + k * 8]);
}

// ---------------- K2: fused projection GEMM ----------------
// Outputs stored FRAGMENT-MAJOR for the attention kernel's 32x32 MFMA:
//  Q/K: f[(w/32)][(o/16)][lane=((o>>3)&1)*32 + (w&31)][e=o&7]  (1KB/frag)
//  V:   f[(c/32)][(j/16)][lane=((j>>3)&1)*32 + (c&31)][e=j&7]  (1KB/frag)
#define PADW 40
__global__ __launch_bounds__(256) void gemm_proj(
    const u16* __restrict__ Wall, const float* __restrict__ ball,
    const u16* __restrict__ xbT, u16* __restrict__ qf,
    u16* __restrict__ kf, u16* __restrict__ vf){
  __shared__ u16 at[64][PADW];
  __shared__ u16 bt[64][PADW];
  int b = blockIdx.z;
  int m0 = blockIdx.y * 64, n0 = blockIdx.x * 64;
  int tid = threadIdx.x, lane = tid & 63, wid = tid >> 6;
  int wm = wid >> 1, wn = wid & 1;
  int g = lane >> 4, r = lane & 15;
  const u16* xb = xbT + (size_t)b * W_ * C_;
  f32x4 acc[2][2] = {};
  int srow = tid >> 2, sseg = (tid & 3) * 8;
  for (int kk = 0; kk < 16; kk++){
    int c0 = kk * 32;
    *(u16x8*)&at[srow][sseg] = *(const u16x8*)&Wall[(size_t)(m0 + srow) * C_ + c0 + sseg];
    *(u16x8*)&bt[srow][sseg] = *(const u16x8*)&xb[(size_t)(n0 + srow) * C_ + c0 + sseg];
    barrier_lds_only();
    bf16x8 a0 = ldb(&at[wm * 32 +  0 + r][g * 8]);
    bf16x8 a1 = ldb(&at[wm * 32 + 16 + r][g * 8]);
    bf16x8 b0 = ldb(&bt[wn * 32 +  0 + r][g * 8]);
    bf16x8 b1 = ldb(&bt[wn * 32 + 16 + r][g * 8]);
    acc[0][0] = mfma16(a0, b0, acc[0][0]);
    acc[0][1] = mfma16(a0, b1, acc[0][1]);
    acc[1][0] = mfma16(a1, b0, acc[1][0]);
    acc[1][1] = mfma16(a1, b1, acc[1][1]);
    barrier_lds_only();
  }
  // epilogue: bias + store fragment-major
  #pragma unroll
  for (int i = 0; i < 2; i++){
    #pragma unroll
    for (int n = 0; n < 2; n++){
      int rbase = m0 + wm * 32 + i * 16 + g * 4;       // stacked row (o or c+128)
      int wcol  = n0 + wn * 32 + n * 16 + r;           // w (i or j)
      if (m0 < 128){
        u16* base = (m0 == 0 ? qf : kf) + (size_t)b * W_ * CO_;
        int o0 = (rbase & 63);
        int oc = o0 >> 4, h2 = (o0 >> 3) & 1, e0 = o0 & 7;
        u16x4 pk;
        #pragma unroll
        for (int t = 0; t < 4; t++) pk[t] = f2b(acc[i][n][t] + ball[rbase + t]);
        *(u16x4*)&base[((size_t)((wcol >> 5) * 4 + oc) * 64 + h2 * 32 + (wcol & 31)) * 8 + e0] = pk;
      } else {
        u16* vb = vf + (size_t)b * C_ * W_;
        int jt = wcol >> 4, h2 = (wcol >> 3) & 1, e = wcol & 7;
        #pragma unroll
        for (int t = 0; t < 4; t++){
          int c = rbase + t - 128;
          vb[((size_t)((c >> 5) * (W_ / 16) + jt) * 64 + h2 * 32 + (c & 31)) * 8 + e] =
              f2b(acc[i][n][t] + ball[rbase + t]);
        }
      }
    }
  }
}

// ---------------- K3: P-shared flash attention v13 (c=128/wave) -----------
// 512 blocks x 256 thr. b=bid&7, i0=(bid>>3)*32. Block covers FULL C=512:
// wave wv owns c = wv*128 (4 c-tiles, acc 64 AGPR). S computed once per
// (b,i0) per j-tile (wave wv sphases tile 4m+wv). Raw barriers (T3/T4),
// rolling 2-set V prefetch (fvX/fvY), setprio on PV (T5), no-max exp2 SM.
__global__ __launch_bounds__(256, 2) void attn13(
    const u16* __restrict__ qf, const u16* __restrict__ kf,
    const u16* __restrict__ vf, const float* __restrict__ x,
    const float* __restrict__ gamma, float* __restrict__ out){
  __shared__ u16 pb[2][32][132];      // P double buffer, [i][j(swizzled)]
  __shared__ float lredf[4][32];      // per-wave row-sum partials
  int tid = threadIdx.x, lane = tid & 63, wv = tid >> 6;
  int bid = blockIdx.x;
  int b = bid & 7;
  int i0 = (bid >> 3) * 32;
  int cbase = wv * 128;
  int li = lane & 31, hi = lane >> 5;
  int swz = (li & 7) << 3;             // XOR key, bits 3..5 of j
  const u16* qfb = qf + (size_t)b * W_ * CO_;
  const u16* kfb = kf + (size_t)b * W_ * CO_;
  const u16* vfb = vf + (size_t)b * C_ * W_;

  // Q B-frags: qf[(i0/32)][oc][lane][8]
  bf16x8 fq[4];
  {
    const u16* qp = &qfb[(size_t)(i0 >> 5) * 4 * 512 + lane * 8];
    #pragma unroll
    for (int oc = 0; oc < 4; oc++) fq[oc] = ldb(qp + oc * 512);
  }

  // streaming bases: K for this wave's own j-tiles (4m+wv); V 4 c-tiles
  const u16* kp = &kfb[(size_t)wv * 2048 + lane * 8];   // += 8192 per macro
  const u16* vpt0 = &vfb[(size_t)(cbase >> 5) * (W_ / 16) * 512 + lane * 8];
  const u16* vpt1 = vpt0 + (size_t)(W_ / 16) * 512;
  const u16* vpt2 = vpt0 + (size_t)2 * (W_ / 16) * 512;
  const u16* vpt3 = vpt0 + (size_t)3 * (W_ / 16) * 512;

  f32x16 acc0 = {}, acc1 = {}, acc2 = {}, acc3 = {};
  f32x4 lacc = {};

  // softmax + P-write for one j-tile from fk, into buffer bsel
  auto sphase = [&](bf16x8 (&fk)[4], int bsel){
    f32x16 S = {};
    S = mfma32(fk[0], fq[0], S);
    S = mfma32(fk[1], fq[1], S);
    S = mfma32(fk[2], fq[2], S);
    S = mfma32(fk[3], fq[3], S);
    float p[16];
    #pragma unroll
    for (int t = 0; t < 16; t++) p[t] = exp2g(S[t]);
    #pragma unroll
    for (int t = 0; t < 4; t++)
      lacc[t] += ((p[t] + p[4 + t]) + (p[8 + t] + p[12 + t]));
    #pragma unroll
    for (int B = 0; B < 4; B++){
      unsigned lo = pkbf(p[4 * B + 0], p[4 * B + 1]);
      unsigned h2 = pkbf(p[4 * B + 2], p[4 * B + 3]);
      int j0 = (wv * 32 + 8 * B + 4 * hi) ^ swz;
      u32x2 wpair = {lo, h2};
      *(u32x2*)&pb[bsel][li][j0] = wpair;
    }
  };
  // read P B-frag for (j-tile jj, K-chunk kj) from buffer bsel
  auto pfrag = [&](int bsel, int jj, int kj) -> bf16x8 {
    int j0 = (jj * 32 + kj * 16 + 8 * hi) ^ swz;
    u16x4 a = *(const u16x4*)&pb[bsel][li][j0];
    u16x4 c = *(const u16x4*)&pb[bsel][li][j0 + 4];
    u16x8 w = {a[0], a[1], a[2], a[3], c[0], c[1], c[2], c[3]};
    return __builtin_bit_cast(bf16x8, w);
  };
  // load the 8 V frags (4 c-tiles x 2 K-chunks) for one jj at u16 offset
  auto loadV = [&](bf16x8 (&fv)[8], int off){
    fv[0] = ldb(vpt0 + off); fv[1] = ldb(vpt0 + off + 512);
    fv[2] = ldb(vpt1 + off); fv[3] = ldb(vpt1 + off + 512);
    fv[4] = ldb(vpt2 + off); fv[5] = ldb(vpt2 + off + 512);
    fv[6] = ldb(vpt3 + off); fv[7] = ldb(vpt3 + off + 512);
  };
  auto PV = [&](bf16x8 (&fv)[8], bf16x8 pf0, bf16x8 pf1){
    __builtin_amdgcn_s_setprio(1);
    acc0 = mfma32(fv[0], pf0, acc0); acc0 = mfma32(fv[1], pf1, acc0);
    acc1 = mfma32(fv[2], pf0, acc1); acc1 = mfma32(fv[3], pf1, acc1);
    acc2 = mfma32(fv[4], pf0, acc2); acc2 = mfma32(fv[5], pf1, acc2);
    acc3 = mfma32(fv[6], pf0, acc3); acc3 = mfma32(fv[7], pf1, acc3);
    __builtin_amdgcn_s_setprio(0);
  };

  bf16x8 fvX[8], fvY[8];
  // prologue: S(macro 0) -> buf 0; V jj0 of macro 0 in flight
  {
    bf16x8 fk[4];
    #pragma unroll
    for (int oc = 0; oc < 4; oc++) fk[oc] = ldb(kp + oc * 512);
    sphase(fk, 0);
  }
  loadV(fvX, 0);
  barrier_lds_only();

  int cur = 0;
  for (int m = 0; m < 16; ++m){
    // K loads for macro m+1 (own j-tile) — consumed in sphase at macro end
    bf16x8 fkN[4];
    if (m < 15){
      const u16* kpn = kp + 8192;
      #pragma unroll
      for (int oc = 0; oc < 4; oc++) fkN[oc] = ldb(kpn + oc * 512);
    }
    // jj0: prefetch jj1, PV from fvX
    loadV(fvY, 1024);
    { bf16x8 pf0 = pfrag(cur, 0, 0), pf1 = pfrag(cur, 0, 1); PV(fvX, pf0, pf1); }
    // jj1: prefetch jj2, PV from fvY
    loadV(fvX, 2048);
    { bf16x8 pf0 = pfrag(cur, 1, 0), pf1 = pfrag(cur, 1, 1); PV(fvY, pf0, pf1); }
    // jj2: prefetch jj3, PV from fvX
    loadV(fvY, 3072);
    { bf16x8 pf0 = pfrag(cur, 2, 0), pf1 = pfrag(cur, 2, 1); PV(fvX, pf0, pf1); }
    // jj3: prefetch next macro's jj0, PV from fvY
    if (m < 15) loadV(fvX, 4096);
    { bf16x8 pf0 = pfrag(cur, 3, 0), pf1 = pfrag(cur, 3, 1); PV(fvY, pf0, pf1); }
    // S + P-write for macro m+1 into the other buffer
    if (m < 15) sphase(fkN, cur ^ 1);
    kp += 8192; vpt0 += 4096; vpt1 += 4096; vpt2 += 4096; vpt3 += 4096;
    // raw barrier: LDS drained, VMEM prefetches stay in flight (T3/T4)
    barrier_lds_only();
    cur ^= 1;
  }

  // cross-wave l reduction: l(i) = sum over 4 waves' j-tile partials
  float l = (lacc[0] + lacc[1]) + (lacc[2] + lacc[3]);
  l = red_sum32(l);
  if (hi == 0) lredf[wv][li] = l;
  __syncthreads();
  float lfull = (lredf[0][li] + lredf[1][li]) + (lredf[2][li] + lredf[3][li]);

  float gm = gamma[0];
  float iv = 1.f / lfull;
  const float* xb = x + (size_t)b * C_ * W_;
  float* ob = out + (size_t)b * C_ * W_;
  int icol = i0 + li;
  auto epi = [&](f32x16 &acc, int ct){
    #pragma unroll
    for (int t = 0; t < 16; t++){
      int crow = (t & 3) + 8 * (t >> 2) + 4 * hi;
      int c = cbase + ct * 32 + crow;
      ob[(size_t)c * W_ + icol] = gm * (acc[t] * iv) + xb[(size_t)c * W_ + icol];
    }
  };
  epi(acc0, 0); epi(acc1, 1); epi(acc2, 2); epi(acc3, 3);
}

extern "C" void kernel_launch(void* const* d_in, const int* in_sizes, int n_in,
                              void* d_out, int out_size, void* d_ws, size_t ws_size,
                              hipStream_t stream) {
  const float* x     = (const float*)d_in[0];
  const float* Wq    = (const float*)d_in[1];
  const float* bq    = (const float*)d_in[2];
  const float* Wk    = (const float*)d_in[3];
  const float* bk    = (const float*)d_in[4];
  const float* Wv    = (const float*)d_in[5];
  const float* bv    = (const float*)d_in[6];
  const float* gamma = (const float*)d_in[7];
  float* out = (float*)d_out;
  char* ws = (char*)d_ws;
  // workspace layout (~38.4 MB total)
  u16*   Wall = (u16*)  (ws + 0);         // 640*512*2        = 655360
  float* ball = (float*)(ws + 655360);    // 640*4            = 2560
  u16*   xbT  = (u16*)  (ws + 657920);    // 8*2048*512*2     = 16777216
  u16*   qf   = (u16*)  (ws + 17435136);  // 8*2048*64*2      = 2097152
  u16*   kf   = (u16*)  (ws + 19532288);  // 8*2048*64*2      = 2097152
  u16*   vf   = (u16*)  (ws + 21629440);  // 8*512*2048*2     = 16777216

  prep_w<<<dim3(1280), dim3(256), 0, stream>>>(Wq, bq, Wk, bk, Wv, bv, Wall, ball);
  xpose<<<dim3(64, 16, 8), dim3(256), 0, stream>>>(x, xbT);
  gemm_proj<<<dim3(32, 10, 8), dim3(256), 0, stream>>>(Wall, ball, xbT, qf, kf, vf);
  attn13<<<dim3(512), dim3(256), 0, stream>>>(qf, kf, vf, x, gamma, out);
}

// Round 15
// 97.393 us; speedup vs baseline: 1.4609x; 1.0595x over previous
//
#include <hip/hip_runtime.h>
#include <stdint.h>

// Problem constants (SelfAttention: B=8, C=512, C8=64, W=2048)
#define B_  8
#define C_  512
#define CO_ 64
#define W_  2048
#define R_  640   // stacked projection rows: 64 q + 64 k + 512 v
#define LOG2E 1.4426950408889634f

typedef float f32x4 __attribute__((ext_vector_type(4)));
typedef float f32x16 __attribute__((ext_vector_type(16)));
typedef __bf16 bf16x8 __attribute__((ext_vector_type(8)));
typedef __bf16 bf16x2 __attribute__((ext_vector_type(2)));
typedef unsigned u32x2 __attribute__((ext_vector_type(2)));
typedef unsigned u32x4 __attribute__((ext_vector_type(4)));
typedef unsigned short u16;
typedef u16 u16x8 __attribute__((ext_vector_type(8)));
typedef u16 u16x4 __attribute__((ext_vector_type(4)));

static __device__ __forceinline__ float exp2g(float f){
  return __builtin_amdgcn_exp2f(f);    // v_exp_f32 (2^x)
}
static __device__ __forceinline__ u16 f2b(float f){
  union { float f; unsigned u; } v; v.f = f;
  unsigned r = v.u + 0x7FFFu + ((v.u >> 16) & 1u);  // RNE
  return (u16)(r >> 16);
}
static __device__ __forceinline__ bf16x8 ldb(const u16* p){
  return __builtin_bit_cast(bf16x8, *(const u16x8*)p);
}
static __device__ __forceinline__ f32x4 mfma16(bf16x8 a, bf16x8 b, f32x4 c){
  return __builtin_amdgcn_mfma_f32_16x16x32_bf16(a, b, c, 0, 0, 0);
}
static __device__ __forceinline__ f32x16 mfma32(bf16x8 a, bf16x8 b, f32x16 c){
  return __builtin_amdgcn_mfma_f32_32x32x16_bf16(a, b, c, 0, 0, 0);
}
// v_permlane32_swap_b32: vdst lanes[32:63] <-> vsrc lanes[0:31]
static __device__ __forceinline__ void pl32swap(unsigned &a, unsigned &b){
  asm("v_permlane32_swap_b32 %0, %1" : "+v"(a), "+v"(b));
}
static __device__ __forceinline__ float red_sum32(float v){
  unsigned a = __builtin_bit_cast(unsigned, v), b = a;
  pl32swap(a, b);
  return __builtin_bit_cast(float, a) + __builtin_bit_cast(float, b);
}
static __device__ __forceinline__ unsigned pkbf(float lo, float hi){
  bf16x2 t; t[0] = (__bf16)lo; t[1] = (__bf16)hi;
  return __builtin_bit_cast(unsigned, t);
}
// raw barrier: drain ONLY LDS (lgkmcnt); VMEM prefetches stay in flight
static __device__ __forceinline__ void barrier_lds_only(){
  asm volatile("s_waitcnt lgkmcnt(0)" ::: "memory");
  __builtin_amdgcn_s_barrier();
}

// ---------------- K0: stack + cast weights/bias to bf16 ----------------
// Q rows are pre-scaled by log2(e) so attention softmax can use raw exp2.
__global__ __launch_bounds__(256) void prep_w(
    const float* __restrict__ Wq, const float* __restrict__ bq,
    const float* __restrict__ Wk, const float* __restrict__ bk,
    const float* __restrict__ Wv, const float* __restrict__ bv,
    u16* __restrict__ Wall, float* __restrict__ ball){
  int e = blockIdx.x * 256 + threadIdx.x;
  if (e < R_ * C_){
    int r = e >> 9, c = e & (C_ - 1);
    float w;
    if (r < 64)       w = Wq[r * C_ + c] * LOG2E;
    else if (r < 128) w = Wk[(r - 64) * C_ + c];
    else              w = Wv[(r - 128) * C_ + c];
    Wall[e] = f2b(w);
  }
  if (e < R_){
    float bb;
    if (e < 64)       bb = bq[e] * LOG2E;
    else if (e < 128) bb = bk[e - 64];
    else              bb = bv[e - 128];
    ball[e] = bb;
  }
}

// ---------------- K1: x [b][c][w] f32 -> xbT [b][w][c] bf16 ----------------
__global__ __launch_bounds__(256) void xpose(const float* __restrict__ x,
                                             u16* __restrict__ xbT){
  __shared__ float t[32][33];
  int b = blockIdx.z, c0 = blockIdx.y * 32, w0 = blockIdx.x * 32;
  int tx = threadIdx.x & 31, ty = threadIdx.x >> 5;   // ty 0..7
  const float* xb = x + (size_t)b * C_ * W_;
  #pragma unroll
  for (int k = 0; k < 4; k++)
    t[ty + k * 8][tx] = xb[(size_t)(c0 + ty + k * 8) * W_ + w0 + tx];
  __syncthreads();
  u16* ob = xbT + (size_t)b * W_ * C_;
  #pragma unroll
  for (int k = 0; k < 4; k++)
    ob[(size_t)(w0 + ty + k * 8) * C_ + c0 + tx] = f2b(t[tx][ty + k * 8]);
}

// ---------------- K2: fused projection GEMM ----------------
// Outputs stored FRAGMENT-MAJOR for the attention kernel's 32x32 MFMA:
//  Q/K: f[(w/32)][(o/16)][lane=((o>>3)&1)*32 + (w&31)][e=o&7]  (1KB/frag)
//  V:   f[(c/32)][(j/16)][lane=((j>>3)&1)*32 + (c&31)][e=j&7]  (1KB/frag)
#define PADW 40
__global__ __launch_bounds__(256) void gemm_proj(
    const u16* __restrict__ Wall, const float* __restrict__ ball,
    const u16* __restrict__ xbT, u16* __restrict__ qf,
    u16* __restrict__ kf, u16* __restrict__ vf){
  __shared__ u16 at[64][PADW];
  __shared__ u16 bt[64][PADW];
  int b = blockIdx.z;
  int m0 = blockIdx.y * 64, n0 = blockIdx.x * 64;
  int tid = threadIdx.x, lane = tid & 63, wid = tid >> 6;
  int wm = wid >> 1, wn = wid & 1;
  int g = lane >> 4, r = lane & 15;
  const u16* xb = xbT + (size_t)b * W_ * C_;
  f32x4 acc[2][2] = {};
  int srow = tid >> 2, sseg = (tid & 3) * 8;
  for (int kk = 0; kk < 16; kk++){
    int c0 = kk * 32;
    *(u16x8*)&at[srow][sseg] = *(const u16x8*)&Wall[(size_t)(m0 + srow) * C_ + c0 + sseg];
    *(u16x8*)&bt[srow][sseg] = *(const u16x8*)&xb[(size_t)(n0 + srow) * C_ + c0 + sseg];
    barrier_lds_only();
    bf16x8 a0 = ldb(&at[wm * 32 +  0 + r][g * 8]);
    bf16x8 a1 = ldb(&at[wm * 32 + 16 + r][g * 8]);
    bf16x8 b0 = ldb(&bt[wn * 32 +  0 + r][g * 8]);
    bf16x8 b1 = ldb(&bt[wn * 32 + 16 + r][g * 8]);
    acc[0][0] = mfma16(a0, b0, acc[0][0]);
    acc[0][1] = mfma16(a0, b1, acc[0][1]);
    acc[1][0] = mfma16(a1, b0, acc[1][0]);
    acc[1][1] = mfma16(a1, b1, acc[1][1]);
    barrier_lds_only();
  }
  // epilogue: bias + store fragment-major
  #pragma unroll
  for (int i = 0; i < 2; i++){
    #pragma unroll
    for (int n = 0; n < 2; n++){
      int rbase = m0 + wm * 32 + i * 16 + g * 4;       // stacked row (o or c+128)
      int wcol  = n0 + wn * 32 + n * 16 + r;           // w (i or j)
      if (m0 < 128){
        u16* base = (m0 == 0 ? qf : kf) + (size_t)b * W_ * CO_;
        int o0 = (rbase & 63);
        int oc = o0 >> 4, h2 = (o0 >> 3) & 1, e0 = o0 & 7;
        u16x4 pk;
        #pragma unroll
        for (int t = 0; t < 4; t++) pk[t] = f2b(acc[i][n][t] + ball[rbase + t]);
        *(u16x4*)&base[((size_t)((wcol >> 5) * 4 + oc) * 64 + h2 * 32 + (wcol & 31)) * 8 + e0] = pk;
      } else {
        u16* vb = vf + (size_t)b * C_ * W_;
        int jt = wcol >> 4, h2 = (wcol >> 3) & 1, e = wcol & 7;
        #pragma unroll
        for (int t = 0; t < 4; t++){
          int c = rbase + t - 128;
          vb[((size_t)((c >> 5) * (W_ / 16) + jt) * 64 + h2 * 32 + (c & 31)) * 8 + e] =
              f2b(acc[i][n][t] + ball[rbase + t]);
        }
      }
    }
  }
}

// ---------------- K3: P-shared flash attention v14 (i=64/block) -----------
// 256 blocks x 512 thr (8 waves, 1 block/CU). b=bid&7, i0=(bid>>3)*64.
// Wave wv: owns c = wv*64 (2 c-tiles) for BOTH 32-row i-tiles -> acc 64 AGPR,
// V frags reused 2x. sphase: wave (jw=wv&3, iw=wv>>2) computes S(j-tile
// 4m+jw, i-tile iw) once. V L2 traffic per batch HALVED vs v13 (32 blocks
// re-read V, not 64). Raw barriers (T3/T4), rolling V prefetch, T5 setprio.
__global__ __launch_bounds__(512, 2) void attn14(
    const u16* __restrict__ qf, const u16* __restrict__ kf,
    const u16* __restrict__ vf, const float* __restrict__ x,
    const float* __restrict__ gamma, float* __restrict__ out){
  __shared__ u16 pb[2][2][32][132];   // P dbuf, [buf][i-tile][i][j(swz)]
  __shared__ float lredf[2][4][32];   // per (i-tile, j-slot) row sums
  int tid = threadIdx.x, lane = tid & 63, wv = tid >> 6;
  int jw = wv & 3, iw = wv >> 2;
  int bid = blockIdx.x;
  int b = bid & 7;
  int i0 = (bid >> 3) * 64;
  int cbase = wv * 64;
  int li = lane & 31, hi = lane >> 5;
  int swz = (li & 7) << 3;             // XOR key, bits 3..5 of j
  const u16* qfb = qf + (size_t)b * W_ * CO_;
  const u16* kfb = kf + (size_t)b * W_ * CO_;
  const u16* vfb = vf + (size_t)b * C_ * W_;

  // Q B-frags for sphase i-tile iw: qf[(i0/32)+iw][oc][lane][8]
  bf16x8 fq[4];
  {
    const u16* qp = &qfb[(size_t)((i0 >> 5) + iw) * 4 * 512 + lane * 8];
    #pragma unroll
    for (int oc = 0; oc < 4; oc++) fq[oc] = ldb(qp + oc * 512);
  }

  // streaming bases: K for j-slot jw; V for the wave's 2 c-tiles
  const u16* kp = &kfb[(size_t)jw * 2048 + lane * 8];   // += 8192 per macro
  const u16* vpt0 = &vfb[(size_t)(cbase >> 5) * (W_ / 16) * 512 + lane * 8];
  const u16* vpt1 = vpt0 + (size_t)(W_ / 16) * 512;

  f32x16 acc00 = {}, acc01 = {}, acc10 = {}, acc11 = {};  // [ct][it]
  f32x4 lacc = {};

  // softmax + P-write for j-tile (4m+jw), i-tile iw, into buffer bsel
  auto sphase = [&](bf16x8 (&fk)[4], int bsel){
    f32x16 S = {};
    S = mfma32(fk[0], fq[0], S);
    S = mfma32(fk[1], fq[1], S);
    S = mfma32(fk[2], fq[2], S);
    S = mfma32(fk[3], fq[3], S);
    float p[16];
    #pragma unroll
    for (int t = 0; t < 16; t++) p[t] = exp2g(S[t]);
    #pragma unroll
    for (int t = 0; t < 4; t++)
      lacc[t] += ((p[t] + p[4 + t]) + (p[8 + t] + p[12 + t]));
    #pragma unroll
    for (int B = 0; B < 4; B++){
      unsigned lo = pkbf(p[4 * B + 0], p[4 * B + 1]);
      unsigned h2 = pkbf(p[4 * B + 2], p[4 * B + 3]);
      int j0 = (jw * 32 + 8 * B + 4 * hi) ^ swz;
      u32x2 wpair = {lo, h2};
      *(u32x2*)&pb[bsel][iw][li][j0] = wpair;
    }
  };
  // read P B-frag for (i-tile it, j-tile jj, K-chunk kj) from buffer bsel
  auto pfrag = [&](int bsel, int it, int jj, int kj) -> bf16x8 {
    int j0 = (jj * 32 + kj * 16 + 8 * hi) ^ swz;
    u16x4 a = *(const u16x4*)&pb[bsel][it][li][j0];
    u16x4 c = *(const u16x4*)&pb[bsel][it][li][j0 + 4];
    u16x8 w = {a[0], a[1], a[2], a[3], c[0], c[1], c[2], c[3]};
    return __builtin_bit_cast(bf16x8, w);
  };
  // load the 4 V frags (2 c-tiles x 2 K-chunks) for one jj at u16 offset
  auto loadV = [&](bf16x8 (&fv)[4], int off){
    fv[0] = ldb(vpt0 + off); fv[1] = ldb(vpt0 + off + 512);
    fv[2] = ldb(vpt1 + off); fv[3] = ldb(vpt1 + off + 512);
  };
  // PV for one jj: V frags x P frags of both i-tiles (V reused 2x)
  auto PV = [&](bf16x8 (&fv)[4], int bsel, int jj){
    bf16x8 p00 = pfrag(bsel, 0, jj, 0), p01 = pfrag(bsel, 0, jj, 1);
    bf16x8 p10 = pfrag(bsel, 1, jj, 0), p11 = pfrag(bsel, 1, jj, 1);
    __builtin_amdgcn_s_setprio(1);
    acc00 = mfma32(fv[0], p00, acc00); acc00 = mfma32(fv[1], p01, acc00);
    acc10 = mfma32(fv[2], p00, acc10); acc10 = mfma32(fv[3], p01, acc10);
    acc01 = mfma32(fv[0], p10, acc01); acc01 = mfma32(fv[1], p11, acc01);
    acc11 = mfma32(fv[2], p10, acc11); acc11 = mfma32(fv[3], p11, acc11);
    __builtin_amdgcn_s_setprio(0);
  };

  bf16x8 fvX[4], fvY[4];
  // prologue: S(macro 0) -> buf 0; V jj0 of macro 0 in flight
  {
    bf16x8 fk[4];
    #pragma unroll
    for (int oc = 0; oc < 4; oc++) fk[oc] = ldb(kp + oc * 512);
    sphase(fk, 0);
  }
  loadV(fvX, 0);
  barrier_lds_only();

  int cur = 0;
  for (int m = 0; m < 16; ++m){
    // K loads for macro m+1 (own j-slot) — consumed in sphase at macro end
    bf16x8 fkN[4];
    if (m < 15){
      const u16* kpn = kp + 8192;
      #pragma unroll
      for (int oc = 0; oc < 4; oc++) fkN[oc] = ldb(kpn + oc * 512);
    }
    // jj0: prefetch jj1, PV from fvX
    loadV(fvY, 1024);
    PV(fvX, cur, 0);
    // jj1: prefetch jj2, PV from fvY
    loadV(fvX, 2048);
    PV(fvY, cur, 1);
    // jj2: prefetch jj3, PV from fvX
    loadV(fvY, 3072);
    PV(fvX, cur, 2);
    // jj3: prefetch next macro's jj0, PV from fvY
    if (m < 15) loadV(fvX, 4096);
    PV(fvY, cur, 3);
    // S + P-write for macro m+1 into the other buffer
    if (m < 15) sphase(fkN, cur ^ 1);
    kp += 8192; vpt0 += 4096; vpt1 += 4096;
    // raw barrier: LDS drained, VMEM prefetches stay in flight (T3/T4)
    barrier_lds_only();
    cur ^= 1;
  }

  // l reduction: wave (jw,iw) has partial row sums for i-tile iw
  float l = (lacc[0] + lacc[1]) + (lacc[2] + lacc[3]);
  l = red_sum32(l);
  if (hi == 0) lredf[iw][jw][li] = l;
  __syncthreads();
  float lf0 = (lredf[0][0][li] + lredf[0][1][li]) + (lredf[0][2][li] + lredf[0][3][li]);
  float lf1 = (lredf[1][0][li] + lredf[1][1][li]) + (lredf[1][2][li] + lredf[1][3][li]);

  float gm = gamma[0];
  float iv0 = 1.f / lf0, iv1 = 1.f / lf1;
  const float* xb = x + (size_t)b * C_ * W_;
  float* ob = out + (size_t)b * C_ * W_;
  auto epi = [&](f32x16 &acc, int ct, int it, float iv){
    int icol = i0 + it * 32 + li;
    #pragma unroll
    for (int t = 0; t < 16; t++){
      int crow = (t & 3) + 8 * (t >> 2) + 4 * hi;
      int c = cbase + ct * 32 + crow;
      ob[(size_t)c * W_ + icol] = gm * (acc[t] * iv) + xb[(size_t)c * W_ + icol];
    }
  };
  epi(acc00, 0, 0, iv0); epi(acc10, 1, 0, iv0);
  epi(acc01, 0, 1, iv1); epi(acc11, 1, 1, iv1);
}

extern "C" void kernel_launch(void* const* d_in, const int* in_sizes, int n_in,
                              void* d_out, int out_size, void* d_ws, size_t ws_size,
                              hipStream_t stream) {
  const float* x     = (const float*)d_in[0];
  const float* Wq    = (const float*)d_in[1];
  const float* bq    = (const float*)d_in[2];
  const float* Wk    = (const float*)d_in[3];
  const float* bk    = (const float*)d_in[4];
  const float* Wv    = (const float*)d_in[5];
  const float* bv    = (const float*)d_in[6];
  const float* gamma = (const float*)d_in[7];
  float* out = (float*)d_out;
  char* ws = (char*)d_ws;
  // workspace layout (~38.4 MB total)
  u16*   Wall = (u16*)  (ws + 0);         // 640*512*2        = 655360
  float* ball = (float*)(ws + 655360);    // 640*4            = 2560
  u16*   xbT  = (u16*)  (ws + 657920);    // 8*2048*512*2     = 16777216
  u16*   qf   = (u16*)  (ws + 17435136);  // 8*2048*64*2      = 2097152
  u16*   kf   = (u16*)  (ws + 19532288);  // 8*2048*64*2      = 2097152
  u16*   vf   = (u16*)  (ws + 21629440);  // 8*512*2048*2     = 16777216

  prep_w<<<dim3(1280), dim3(256), 0, stream>>>(Wq, bq, Wk, bk, Wv, bv, Wall, ball);
  xpose<<<dim3(64, 16, 8), dim3(256), 0, stream>>>(x, xbT);
  gemm_proj<<<dim3(32, 10, 8), dim3(256), 0, stream>>>(Wall, ball, xbT, qf, kf, vf);
  attn14<<<dim3(256), dim3(512), 0, stream>>>(qf, kf, vf, x, gamma, out);
}